// Round 10
// baseline (648.219 us; speedup 1.0000x reference)
//
#include <hip/hip_runtime.h>

#define DIN  32
#define DH   64
#define DOUT 16
#define SCAN_BLK 1024   // elements per scan block; supports N <= 262144
#define BKT_SHIFT 7     // 128 nodes per bucket
#define BKT_NODES 128
#define MAXSEG 8192     // LDS segment cap (32KB); P(seg>cap) ~ 0 for Poisson(2048)

// ------------------------------------------------------------ degree count --
__global__ void k_count_deg(const int* __restrict__ dst, int* __restrict__ deg, int E) {
    int e = blockIdx.x * blockDim.x + threadIdx.x;
    if (e < E) atomicAdd(&deg[dst[e]], 1);
}

// ------------------------------------------------- scan stage 1: per-block --
__global__ void k_scan1(const int* __restrict__ deg, int* __restrict__ partial,
                        int* __restrict__ blockSums, int N) {
    __shared__ int s[256];
    int tid  = threadIdx.x;
    int base = blockIdx.x * SCAN_BLK + tid * 4;
    int v0 = (base + 0 < N) ? deg[base + 0] : 0;
    int v1 = (base + 1 < N) ? deg[base + 1] : 0;
    int v2 = (base + 2 < N) ? deg[base + 2] : 0;
    int v3 = (base + 3 < N) ? deg[base + 3] : 0;
    int tot = v0 + v1 + v2 + v3;
    s[tid] = tot;
    __syncthreads();
    for (int off = 1; off < 256; off <<= 1) {
        int t = (tid >= off) ? s[tid - off] : 0;
        __syncthreads();
        s[tid] += t;
        __syncthreads();
    }
    int excl = s[tid] - tot;
    if (base + 0 < N) partial[base + 0] = excl;
    if (base + 1 < N) partial[base + 1] = excl + v0;
    if (base + 2 < N) partial[base + 2] = excl + v0 + v1;
    if (base + 3 < N) partial[base + 3] = excl + v0 + v1 + v2;
    if (tid == 255) blockSums[blockIdx.x] = s[255];
}

// ------------------------------------ scan stage 2: scan block sums (1 blk) --
__global__ void k_scan2(int* __restrict__ blockSums, int* __restrict__ blockOff, int NB) {
    __shared__ int s[256];
    int tid = threadIdx.x;
    int v = (tid < NB) ? blockSums[tid] : 0;
    s[tid] = v;
    __syncthreads();
    for (int off = 1; off < 256; off <<= 1) {
        int t = (tid >= off) ? s[tid - off] : 0;
        __syncthreads();
        s[tid] += t;
        __syncthreads();
    }
    if (tid < NB) blockOff[tid] = s[tid] - v;
}

// ------- scan stage 3: rowStart = partial+blockOff; cursor=rowStart; dinv ---
__global__ void k_scan3(const int* __restrict__ partial, const int* __restrict__ blockOff,
                        const int* __restrict__ deg, int* __restrict__ rowStart,
                        int* __restrict__ cursor, float* __restrict__ dinv, int N) {
    int i = blockIdx.x * blockDim.x + threadIdx.x;
    if (i < N) {
        int rs = partial[i] + blockOff[i / SCAN_BLK];
        rowStart[i] = rs;
        cursor[i]   = rs;
        dinv[i]     = rsqrtf((float)deg[i] + 1.0f); // +1 self-loop
    }
}

// ------------------------------------- bucket cursors = rowStart at bases ---
__global__ void k_bcur(const int* __restrict__ rowStart, int* __restrict__ bcur,
                       int NBUCKETS) {
    int b = blockIdx.x * blockDim.x + threadIdx.x;
    if (b < NBUCKETS) bcur[b] = rowStart[b << BKT_SHIFT];
}

// ---- CSR fill pass A: radix-partition edges into dst-range buckets ----------
// All writes go to ~782 advancing bucket FRONTIERS (~50KB hot set): each line
// fills completely while the frontier crosses it -> line-efficient writes by
// construction, no cache-residency assumption.
__global__ void k_passA(const int* __restrict__ src, const int* __restrict__ dst,
                        int* __restrict__ bcur, int2* __restrict__ pairs, int E) {
    int e = blockIdx.x * blockDim.x + threadIdx.x;
    if (e < E) {
        int d = dst[e];
        int s = src[e];
        int p = atomicAdd(&bcur[d >> BKT_SHIFT], 1);
        int2 pr; pr.x = s; pr.y = d;
        pairs[p] = pr;
    }
}

// ---- CSR fill pass B: place each bucket's segment in LDS, flush coalesced ---
// One block per bucket. Per-node cursors live in LDS (relative to segBase);
// final edgeSrc written as full sequential lines: exactly E*4 bytes.
__global__ void k_passB(const int* __restrict__ rowStart, int* __restrict__ cursor,
                        const int2* __restrict__ pairs, int* __restrict__ edgeSrc,
                        int N, int E) {
    __shared__ int curs[BKT_NODES];
    __shared__ int lsrc[MAXSEG];
    int b    = blockIdx.x;
    int n_lo = b << BKT_SHIFT;
    int n_hi = min(N, n_lo + BKT_NODES);
    int segBase = rowStart[n_lo];
    int segEnd  = (n_hi < N) ? rowStart[n_hi] : E;
    int segLen  = segEnd - segBase;
    int tid = threadIdx.x;

    if (segLen <= MAXSEG) {
        for (int i = tid; i < n_hi - n_lo; i += 256)
            curs[i] = rowStart[n_lo + i] - segBase;
        __syncthreads();
        for (int t = tid; t < segLen; t += 256) {
            int2 pr = pairs[segBase + t];
            int p = atomicAdd(&curs[pr.y - n_lo], 1);   // LDS atomic
            lsrc[p] = pr.x;
        }
        __syncthreads();
        for (int t = tid; t < segLen; t += 256)
            edgeSrc[segBase + t] = lsrc[t];             // coalesced full lines
    } else {
        // statistically-unreachable fallback: global cursor scatter
        for (int t = tid; t < segLen; t += 256) {
            int2 pr = pairs[segBase + t];
            int p = atomicAdd(&cursor[pr.y], 1);
            edgeSrc[p] = pr.x;
        }
    }
}

// ------------------------------------------ xg = dinv[i] * x[i,:], float4 ---
__global__ void k_xg(const float4* __restrict__ x4, const float* __restrict__ dinv,
                     float4* __restrict__ xg4, int N) {
    int t = blockIdx.x * blockDim.x + threadIdx.x;
    if (t < N * 8) {                       // 8 quads per node
        float d = dinv[t >> 3];
        float4 v = x4[t];
        v.x *= d; v.y *= d; v.z *= d; v.w *= d;
        xg4[t] = v;
    }
}

// ---- layer-1 aggregation ONLY (no GEMM): s_i = sum_j xg_j + xg_i -----------
// wave per node. lane = es*8 + fl: es = edge slot (0..7), fl = feature quad.
// First 32 edges as ONE predicated two-stage block; rare loop for deg > 32.
__global__ void k_agg1(const int* __restrict__ rowStart, const int* __restrict__ deg,
                       const int* __restrict__ edgeSrc, const float4* __restrict__ xg4,
                       float4* __restrict__ s4, int N) {
    int tid = threadIdx.x;
    int w = tid >> 6, lane = tid & 63;
    int es = lane >> 3, fl = lane & 7;
    int node = blockIdx.x * 4 + w;   // wave-uniform
    if (node >= N) return;

    int s = rowStart[node], c = deg[node];
    float4 a0 = {0,0,0,0}, a1 = {0,0,0,0}, a2 = {0,0,0,0}, a3 = {0,0,0,0};
    int j0 = 0, j1 = 0, j2 = 0, j3 = 0;
    int o0 = es, o1 = 8 + es, o2 = 16 + es, o3 = 24 + es;
    // stage 1: all index loads in flight together
    if (o0 < c) j0 = edgeSrc[s + o0];
    if (o1 < c) j1 = edgeSrc[s + o1];
    if (o2 < c) j2 = edgeSrc[s + o2];
    if (o3 < c) j3 = edgeSrc[s + o3];
    // stage 2: all payload gathers in flight together (8 edges per instr)
    if (o0 < c) a0 = xg4[(size_t)j0 * 8 + fl];
    if (o1 < c) a1 = xg4[(size_t)j1 * 8 + fl];
    if (o2 < c) a2 = xg4[(size_t)j2 * 8 + fl];
    if (o3 < c) a3 = xg4[(size_t)j3 * 8 + fl];
    // rare long tail (deg > 32)
    for (int o = 32 + es; o < c; o += 8) {
        int j = edgeSrc[s + o];
        float4 v = xg4[(size_t)j * 8 + fl];
        a0.x += v.x; a0.y += v.y; a0.z += v.z; a0.w += v.w;
    }
    float4 A;
    A.x = (a0.x + a1.x) + (a2.x + a3.x);
    A.y = (a0.y + a1.y) + (a2.y + a3.y);
    A.z = (a0.z + a1.z) + (a2.z + a3.z);
    A.w = (a0.w + a1.w) + (a2.w + a3.w);
#pragma unroll
    for (int m = 8; m <= 32; m <<= 1) {   // fold 8 edge slots
        A.x += __shfl_xor(A.x, m);
        A.y += __shfl_xor(A.y, m);
        A.z += __shfl_xor(A.z, m);
        A.w += __shfl_xor(A.w, m);
    }
    if (es == 0) {
        float4 sl = xg4[(size_t)node * 8 + fl];   // self-loop: dinv_i * x_i
        A.x += sl.x; A.y += sl.y; A.z += sl.z; A.w += sl.w;
        s4[(size_t)node * 8 + fl] = A;            // 128B per node, 8 lanes
    }
}

// ---- dense per-node MLP: g2 = dinv*( relu(dinv*(s@W1)+b1) @ W2 ) -----------
// ONE NODE PER LANE. W1/W2/b1 addresses are wave-uniform -> scalar loads;
// s/h/g live in registers; zero LDS, zero shfl. Fully unrolled FMA chain.
__global__ void k_gemm12(const float* __restrict__ s, const float* __restrict__ dinv,
                         const float* __restrict__ b1, const float* __restrict__ W1,
                         const float* __restrict__ W2, float* __restrict__ g2, int N) {
    int node = blockIdx.x * blockDim.x + threadIdx.x;
    if (node >= N) return;

    float sv[DIN];
    const float4* s4 = (const float4*)s;
#pragma unroll
    for (int q = 0; q < 8; ++q) {
        float4 v = s4[(size_t)node * 8 + q];
        sv[4 * q + 0] = v.x; sv[4 * q + 1] = v.y;
        sv[4 * q + 2] = v.z; sv[4 * q + 3] = v.w;
    }

    float h[DH];
#pragma unroll
    for (int k = 0; k < DH; ++k) h[k] = 0.f;
#pragma unroll
    for (int d = 0; d < DIN; ++d) {
#pragma unroll
        for (int k = 0; k < DH; ++k) h[k] += sv[d] * W1[d * DH + k];
    }
    float di = dinv[node];
#pragma unroll
    for (int k = 0; k < DH; ++k) h[k] = fmaxf(di * h[k] + b1[k], 0.f);

    float g[DOUT];
#pragma unroll
    for (int k = 0; k < DOUT; ++k) g[k] = 0.f;
#pragma unroll
    for (int d = 0; d < DH; ++d) {
#pragma unroll
        for (int k = 0; k < DOUT; ++k) g[k] += h[d] * W2[d * DOUT + k];
    }

    float4* g2_4 = (float4*)g2;
#pragma unroll
    for (int q = 0; q < 4; ++q) {
        float4 r;
        r.x = di * g[4 * q + 0]; r.y = di * g[4 * q + 1];
        r.z = di * g[4 * q + 2]; r.w = di * g[4 * q + 3];
        g2_4[(size_t)node * 4 + q] = r;
    }
}

// ---- layer-2 aggregate + finalize -------------------------------------------
// wave per node. lane = es*4 + fl: es = edge slot (0..15), fl = feature quad.
__global__ void k_agg2(const int* __restrict__ rowStart, const int* __restrict__ deg,
                       const int* __restrict__ edgeSrc, const float4* __restrict__ g2_4,
                       const float* __restrict__ dinv, const float* __restrict__ b2,
                       float4* __restrict__ out4, int N) {
    int tid = threadIdx.x;
    int w = tid >> 6, lane = tid & 63;
    int es = lane >> 2, fl = lane & 3;
    int node = blockIdx.x * 4 + w;   // wave-uniform
    if (node >= N) return;

    int s = rowStart[node], c = deg[node];
    float4 a0 = {0,0,0,0}, a1 = {0,0,0,0};
    int j0 = 0, j1 = 0;
    int o0 = es, o1 = 16 + es;
    if (o0 < c) j0 = edgeSrc[s + o0];
    if (o1 < c) j1 = edgeSrc[s + o1];
    if (o0 < c) a0 = g2_4[(size_t)j0 * 4 + fl];
    if (o1 < c) a1 = g2_4[(size_t)j1 * 4 + fl];
    for (int o = 32 + es; o < c; o += 16) {       // rare long tail
        int j = edgeSrc[s + o];
        float4 v = g2_4[(size_t)j * 4 + fl];
        a0.x += v.x; a0.y += v.y; a0.z += v.z; a0.w += v.w;
    }
    float4 A;
    A.x = a0.x + a1.x; A.y = a0.y + a1.y; A.z = a0.z + a1.z; A.w = a0.w + a1.w;
#pragma unroll
    for (int m = 4; m <= 32; m <<= 1) {           // fold 16 edge slots
        A.x += __shfl_xor(A.x, m);
        A.y += __shfl_xor(A.y, m);
        A.z += __shfl_xor(A.z, m);
        A.w += __shfl_xor(A.w, m);
    }
    if (es == 0) {
        float4 sl = g2_4[(size_t)node * 4 + fl];  // self-loop
        A.x += sl.x; A.y += sl.y; A.z += sl.z; A.w += sl.w;
        float d = dinv[node];
        const float4* b2_4 = (const float4*)b2;
        float4 bq = b2_4[fl], r;
        r.x = d * A.x + bq.x; r.y = d * A.y + bq.y;
        r.z = d * A.z + bq.z; r.w = d * A.w + bq.w;
        out4[(size_t)node * 4 + fl] = r;
    }
}

// ----------------------------------------------------------------------------
static inline size_t align16(size_t v) { return (v + 15) & ~(size_t)15; }

extern "C" void kernel_launch(void* const* d_in, const int* in_sizes, int n_in,
                              void* d_out, int out_size, void* d_ws, size_t ws_size,
                              hipStream_t stream) {
    const float* x  = (const float*)d_in[0];
    const int*   ei = (const int*)  d_in[1];
    const float* W1 = (const float*)d_in[2];
    const float* b1 = (const float*)d_in[3];
    const float* W2 = (const float*)d_in[4];
    const float* b2 = (const float*)d_in[5];

    int N = in_sizes[0] / DIN;
    int E = in_sizes[1] / 2;
    const int* src = ei;
    const int* dst = ei + E;
    int NB = (N + SCAN_BLK - 1) / SCAN_BLK;
    int NBUCKETS = (N + BKT_NODES - 1) / BKT_NODES;

    // workspace layout, 16B-aligned regions
    char* base = (char*)d_ws;
    size_t off = 0;
    int*   deg       = (int*)(base + off);   off = align16(off + (size_t)N * 4);
    int*   partial   = (int*)(base + off);   off = align16(off + (size_t)N * 4);
    int*   rowStart  = (int*)(base + off);   off = align16(off + (size_t)N * 4);
    int*   cursor    = (int*)(base + off);   off = align16(off + (size_t)N * 4);
    int*   blockSums = (int*)(base + off);   off = align16(off + 256 * 4);
    int*   blockOff  = (int*)(base + off);   off = align16(off + 256 * 4);
    int*   bcur      = (int*)(base + off);   off = align16(off + (size_t)NBUCKETS * 4);
    float* dinv      = (float*)(base + off); off = align16(off + (size_t)N * 4);
    int*   edgeSrc   = (int*)(base + off);   off = align16(off + (size_t)E * 4);
    float* xg        = (float*)(base + off); off = align16(off + (size_t)N * DIN * 4);
    float* sagg      = (float*)(base + off); off = align16(off + (size_t)N * DIN * 4);
    float* g2        = (float*)(base + off); off = align16(off + (size_t)N * DOUT * 4);
    // pairs (12.8MB, live only passA..passB) aliases sagg (12.8MB, written by
    // k_agg1 strictly after passB completes on the same stream)
    int2*  pairs     = (int2*)sagg;

    hipMemsetAsync(deg, 0, (size_t)N * 4, stream);

    k_count_deg<<<(E + 255) / 256, 256, 0, stream>>>(dst, deg, E);
    k_scan1<<<NB, 256, 0, stream>>>(deg, partial, blockSums, N);
    k_scan2<<<1, 256, 0, stream>>>(blockSums, blockOff, NB);
    k_scan3<<<(N + 255) / 256, 256, 0, stream>>>(partial, blockOff, deg,
                                                 rowStart, cursor, dinv, N);
    k_bcur<<<(NBUCKETS + 255) / 256, 256, 0, stream>>>(rowStart, bcur, NBUCKETS);

    k_passA<<<(E + 255) / 256, 256, 0, stream>>>(src, dst, bcur, pairs, E);
    k_passB<<<NBUCKETS, 256, 0, stream>>>(rowStart, cursor, pairs, edgeSrc, N, E);

    k_xg<<<((size_t)N * 8 + 255) / 256, 256, 0, stream>>>((const float4*)x, dinv,
                                                          (float4*)xg, N);
    k_agg1<<<(N + 3) / 4, 256, 0, stream>>>(rowStart, deg, edgeSrc,
                                            (const float4*)xg, (float4*)sagg, N);
    k_gemm12<<<(N + 255) / 256, 256, 0, stream>>>(sagg, dinv, b1, W1, W2, g2, N);
    k_agg2<<<(N + 3) / 4, 256, 0, stream>>>(rowStart, deg, edgeSrc,
                                            (const float4*)g2, dinv, b2,
                                            (float4*)d_out, N);
}

// Round 11
// 323.003 us; speedup vs baseline: 2.0069x; 2.0069x over previous
//
#include <hip/hip_runtime.h>

#define DIN  32
#define DH   64
#define DOUT 16
#define SCAN_BLK 1024   // elements per scan block; supports N <= 262144
#define NXCD 8

// ------------------------------------------- degree count, int4 + 4-wide ILP
__global__ void k_count_deg(const int* __restrict__ dst, int* __restrict__ deg, int E) {
    int EV = E >> 2;
    int v = blockIdx.x * blockDim.x + threadIdx.x;
    if (v < EV) {
        int4 d4 = ((const int4*)dst)[v];
        atomicAdd(&deg[d4.x], 1);   // 4 independent atomics, pipelined
        atomicAdd(&deg[d4.y], 1);
        atomicAdd(&deg[d4.z], 1);
        atomicAdd(&deg[d4.w], 1);
    }
    // tail (E%4) handled by first threads of block 0
    if (blockIdx.x == 0 && threadIdx.x < (E & 3))
        atomicAdd(&deg[dst[(E & ~3) + threadIdx.x]], 1);
}

// ------------------------------------------------- scan stage 1: per-block --
__global__ void k_scan1(const int* __restrict__ deg, int* __restrict__ partial,
                        int* __restrict__ blockSums, int N) {
    __shared__ int s[256];
    int tid  = threadIdx.x;
    int base = blockIdx.x * SCAN_BLK + tid * 4;
    int v0 = (base + 0 < N) ? deg[base + 0] : 0;
    int v1 = (base + 1 < N) ? deg[base + 1] : 0;
    int v2 = (base + 2 < N) ? deg[base + 2] : 0;
    int v3 = (base + 3 < N) ? deg[base + 3] : 0;
    int tot = v0 + v1 + v2 + v3;
    s[tid] = tot;
    __syncthreads();
    for (int off = 1; off < 256; off <<= 1) {
        int t = (tid >= off) ? s[tid - off] : 0;
        __syncthreads();
        s[tid] += t;
        __syncthreads();
    }
    int excl = s[tid] - tot;
    if (base + 0 < N) partial[base + 0] = excl;
    if (base + 1 < N) partial[base + 1] = excl + v0;
    if (base + 2 < N) partial[base + 2] = excl + v0 + v1;
    if (base + 3 < N) partial[base + 3] = excl + v0 + v1 + v2;
    if (tid == 255) blockSums[blockIdx.x] = s[255];
}

// ------------------------------------ scan stage 2: scan block sums (1 blk) --
__global__ void k_scan2(int* __restrict__ blockSums, int* __restrict__ blockOff, int NB) {
    __shared__ int s[256];
    int tid = threadIdx.x;
    int v = (tid < NB) ? blockSums[tid] : 0;
    s[tid] = v;
    __syncthreads();
    for (int off = 1; off < 256; off <<= 1) {
        int t = (tid >= off) ? s[tid - off] : 0;
        __syncthreads();
        s[tid] += t;
        __syncthreads();
    }
    if (tid < NB) blockOff[tid] = s[tid] - v;
}

// ------- scan stage 3: rowStart = partial+blockOff; cursor=rowStart; dinv ---
__global__ void k_scan3(const int* __restrict__ partial, const int* __restrict__ blockOff,
                        const int* __restrict__ deg, int* __restrict__ rowStart,
                        int* __restrict__ cursor, float* __restrict__ dinv, int N) {
    int i = blockIdx.x * blockDim.x + threadIdx.x;
    if (i < N) {
        int rs = partial[i] + blockOff[i / SCAN_BLK];
        rowStart[i] = rs;
        cursor[i]   = rs;
        dinv[i]     = rsqrtf((float)deg[i] + 1.0f); // +1 self-loop
    }
}

// --------------------------- CSR fill, XCD-binned, split-phase for atomic ILP
// 8 dst-octant tags (blockIdx%8 ~ XCD); per pass each thread handles 2 int4
// groups: phase 1 = 8 range tests + up to 8 INDEPENDENT cursor atomics in
// flight, phase 2 = the dependent stores. Exact per-node cursors: contention
// ~16 hits/counter (safe; coarse-bucket histograms are contention-bound).
__global__ void k_fill(const int* __restrict__ src, const int* __restrict__ dst,
                       int* __restrict__ cursor, int* __restrict__ edgeSrc,
                       int E, int N) {
    int xcd  = blockIdx.x & (NXCD - 1);
    int blk  = blockIdx.x >> 3;
    int nblk = gridDim.x >> 3;
    int lo = (int)(((long long)xcd       * N) / NXCD);
    int hi = (int)(((long long)(xcd + 1) * N) / NXCD);

    int EV = E >> 2;   // int4 groups
    int nthreads = nblk * blockDim.x;
    const int4* d4p = (const int4*)dst;
    const int4* s4p = (const int4*)src;

    if ((E & 3) == 0) {
        for (int v = blk * blockDim.x + threadIdx.x; v < EV; v += 2 * nthreads) {
            int v2i = v + nthreads;
            int4 dA = d4p[v];
            int4 dB = (v2i < EV) ? d4p[v2i] : (int4){-1, -1, -1, -1};
            int4 sA = s4p[v];
            int4 sB = (v2i < EV) ? s4p[v2i] : (int4){0, 0, 0, 0};
            // phase 1: independent atomics (positions), all in flight
            int p0 = -1, p1 = -1, p2 = -1, p3 = -1;
            int q0 = -1, q1 = -1, q2 = -1, q3 = -1;
            if (dA.x >= lo && dA.x < hi) p0 = atomicAdd(&cursor[dA.x], 1);
            if (dA.y >= lo && dA.y < hi) p1 = atomicAdd(&cursor[dA.y], 1);
            if (dA.z >= lo && dA.z < hi) p2 = atomicAdd(&cursor[dA.z], 1);
            if (dA.w >= lo && dA.w < hi) p3 = atomicAdd(&cursor[dA.w], 1);
            if (dB.x >= lo && dB.x < hi) q0 = atomicAdd(&cursor[dB.x], 1);
            if (dB.y >= lo && dB.y < hi) q1 = atomicAdd(&cursor[dB.y], 1);
            if (dB.z >= lo && dB.z < hi) q2 = atomicAdd(&cursor[dB.z], 1);
            if (dB.w >= lo && dB.w < hi) q3 = atomicAdd(&cursor[dB.w], 1);
            // phase 2: dependent stores
            if (p0 >= 0) edgeSrc[p0] = sA.x;
            if (p1 >= 0) edgeSrc[p1] = sA.y;
            if (p2 >= 0) edgeSrc[p2] = sA.z;
            if (p3 >= 0) edgeSrc[p3] = sA.w;
            if (q0 >= 0) edgeSrc[q0] = sB.x;
            if (q1 >= 0) edgeSrc[q1] = sB.y;
            if (q2 >= 0) edgeSrc[q2] = sB.z;
            if (q3 >= 0) edgeSrc[q3] = sB.w;
        }
    } else {
        for (int e = blk * blockDim.x + threadIdx.x; e < E; e += nthreads) {
            int d = dst[e];
            if (d >= lo && d < hi) { int p = atomicAdd(&cursor[d], 1); edgeSrc[p] = src[e]; }
        }
    }
}

// ------------------------------------------ xg = dinv[i] * x[i,:], float4 ---
__global__ void k_xg(const float4* __restrict__ x4, const float* __restrict__ dinv,
                     float4* __restrict__ xg4, int N) {
    int t = blockIdx.x * blockDim.x + threadIdx.x;
    if (t < N * 8) {                       // 8 quads per node
        float d = dinv[t >> 3];
        float4 v = x4[t];
        v.x *= d; v.y *= d; v.z *= d; v.w *= d;
        xg4[t] = v;
    }
}

// ---- layer-1 aggregation ONLY (no GEMM): s_i = sum_j xg_j + xg_i -----------
// wave per node. lane = es*8 + fl: es = edge slot (0..7), fl = feature quad.
// First 32 edges as ONE predicated two-stage block; rare loop for deg > 32.
__global__ void k_agg1(const int* __restrict__ rowStart, const int* __restrict__ deg,
                       const int* __restrict__ edgeSrc, const float4* __restrict__ xg4,
                       float4* __restrict__ s4, int N) {
    int tid = threadIdx.x;
    int w = tid >> 6, lane = tid & 63;
    int es = lane >> 3, fl = lane & 7;
    int node = blockIdx.x * 4 + w;   // wave-uniform
    if (node >= N) return;

    int s = rowStart[node], c = deg[node];
    float4 a0 = {0,0,0,0}, a1 = {0,0,0,0}, a2 = {0,0,0,0}, a3 = {0,0,0,0};
    int j0 = 0, j1 = 0, j2 = 0, j3 = 0;
    int o0 = es, o1 = 8 + es, o2 = 16 + es, o3 = 24 + es;
    // stage 1: all index loads in flight together
    if (o0 < c) j0 = edgeSrc[s + o0];
    if (o1 < c) j1 = edgeSrc[s + o1];
    if (o2 < c) j2 = edgeSrc[s + o2];
    if (o3 < c) j3 = edgeSrc[s + o3];
    // stage 2: all payload gathers in flight together (8 edges per instr)
    if (o0 < c) a0 = xg4[(size_t)j0 * 8 + fl];
    if (o1 < c) a1 = xg4[(size_t)j1 * 8 + fl];
    if (o2 < c) a2 = xg4[(size_t)j2 * 8 + fl];
    if (o3 < c) a3 = xg4[(size_t)j3 * 8 + fl];
    // rare long tail (deg > 32)
    for (int o = 32 + es; o < c; o += 8) {
        int j = edgeSrc[s + o];
        float4 v = xg4[(size_t)j * 8 + fl];
        a0.x += v.x; a0.y += v.y; a0.z += v.z; a0.w += v.w;
    }
    float4 A;
    A.x = (a0.x + a1.x) + (a2.x + a3.x);
    A.y = (a0.y + a1.y) + (a2.y + a3.y);
    A.z = (a0.z + a1.z) + (a2.z + a3.z);
    A.w = (a0.w + a1.w) + (a2.w + a3.w);
#pragma unroll
    for (int m = 8; m <= 32; m <<= 1) {   // fold 8 edge slots
        A.x += __shfl_xor(A.x, m);
        A.y += __shfl_xor(A.y, m);
        A.z += __shfl_xor(A.z, m);
        A.w += __shfl_xor(A.w, m);
    }
    if (es == 0) {
        float4 sl = xg4[(size_t)node * 8 + fl];   // self-loop: dinv_i * x_i
        A.x += sl.x; A.y += sl.y; A.z += sl.z; A.w += sl.w;
        s4[(size_t)node * 8 + fl] = A;            // 128B per node, 8 lanes
    }
}

// ---- dense per-node MLP: g2 = dinv*( relu(dinv*(s@W1)+b1) @ W2 ) -----------
// ONE NODE PER LANE. W1/W2/b1 addresses are wave-uniform -> scalar loads;
// s/h/g live in registers; zero LDS, zero shfl. Fully unrolled FMA chain.
__global__ void k_gemm12(const float* __restrict__ s, const float* __restrict__ dinv,
                         const float* __restrict__ b1, const float* __restrict__ W1,
                         const float* __restrict__ W2, float* __restrict__ g2, int N) {
    int node = blockIdx.x * blockDim.x + threadIdx.x;
    if (node >= N) return;

    float sv[DIN];
    const float4* s4 = (const float4*)s;
#pragma unroll
    for (int q = 0; q < 8; ++q) {
        float4 v = s4[(size_t)node * 8 + q];
        sv[4 * q + 0] = v.x; sv[4 * q + 1] = v.y;
        sv[4 * q + 2] = v.z; sv[4 * q + 3] = v.w;
    }

    float h[DH];
#pragma unroll
    for (int k = 0; k < DH; ++k) h[k] = 0.f;
#pragma unroll
    for (int d = 0; d < DIN; ++d) {
#pragma unroll
        for (int k = 0; k < DH; ++k) h[k] += sv[d] * W1[d * DH + k];
    }
    float di = dinv[node];
#pragma unroll
    for (int k = 0; k < DH; ++k) h[k] = fmaxf(di * h[k] + b1[k], 0.f);

    float g[DOUT];
#pragma unroll
    for (int k = 0; k < DOUT; ++k) g[k] = 0.f;
#pragma unroll
    for (int d = 0; d < DH; ++d) {
#pragma unroll
        for (int k = 0; k < DOUT; ++k) g[k] += h[d] * W2[d * DOUT + k];
    }

    float4* g2_4 = (float4*)g2;
#pragma unroll
    for (int q = 0; q < 4; ++q) {
        float4 r;
        r.x = di * g[4 * q + 0]; r.y = di * g[4 * q + 1];
        r.z = di * g[4 * q + 2]; r.w = di * g[4 * q + 3];
        g2_4[(size_t)node * 4 + q] = r;
    }
}

// ---- layer-2 aggregate + finalize -------------------------------------------
// wave per node. lane = es*4 + fl: es = edge slot (0..15), fl = feature quad.
__global__ void k_agg2(const int* __restrict__ rowStart, const int* __restrict__ deg,
                       const int* __restrict__ edgeSrc, const float4* __restrict__ g2_4,
                       const float* __restrict__ dinv, const float* __restrict__ b2,
                       float4* __restrict__ out4, int N) {
    int tid = threadIdx.x;
    int w = tid >> 6, lane = tid & 63;
    int es = lane >> 2, fl = lane & 3;
    int node = blockIdx.x * 4 + w;   // wave-uniform
    if (node >= N) return;

    int s = rowStart[node], c = deg[node];
    float4 a0 = {0,0,0,0}, a1 = {0,0,0,0};
    int j0 = 0, j1 = 0;
    int o0 = es, o1 = 16 + es;
    if (o0 < c) j0 = edgeSrc[s + o0];
    if (o1 < c) j1 = edgeSrc[s + o1];
    if (o0 < c) a0 = g2_4[(size_t)j0 * 4 + fl];
    if (o1 < c) a1 = g2_4[(size_t)j1 * 4 + fl];
    for (int o = 32 + es; o < c; o += 16) {       // rare long tail
        int j = edgeSrc[s + o];
        float4 v = g2_4[(size_t)j * 4 + fl];
        a0.x += v.x; a0.y += v.y; a0.z += v.z; a0.w += v.w;
    }
    float4 A;
    A.x = a0.x + a1.x; A.y = a0.y + a1.y; A.z = a0.z + a1.z; A.w = a0.w + a1.w;
#pragma unroll
    for (int m = 4; m <= 32; m <<= 1) {           // fold 16 edge slots
        A.x += __shfl_xor(A.x, m);
        A.y += __shfl_xor(A.y, m);
        A.z += __shfl_xor(A.z, m);
        A.w += __shfl_xor(A.w, m);
    }
    if (es == 0) {
        float4 sl = g2_4[(size_t)node * 4 + fl];  // self-loop
        A.x += sl.x; A.y += sl.y; A.z += sl.z; A.w += sl.w;
        float d = dinv[node];
        const float4* b2_4 = (const float4*)b2;
        float4 bq = b2_4[fl], r;
        r.x = d * A.x + bq.x; r.y = d * A.y + bq.y;
        r.z = d * A.z + bq.z; r.w = d * A.w + bq.w;
        out4[(size_t)node * 4 + fl] = r;
    }
}

// ----------------------------------------------------------------------------
static inline size_t align16(size_t v) { return (v + 15) & ~(size_t)15; }

extern "C" void kernel_launch(void* const* d_in, const int* in_sizes, int n_in,
                              void* d_out, int out_size, void* d_ws, size_t ws_size,
                              hipStream_t stream) {
    const float* x  = (const float*)d_in[0];
    const int*   ei = (const int*)  d_in[1];
    const float* W1 = (const float*)d_in[2];
    const float* b1 = (const float*)d_in[3];
    const float* W2 = (const float*)d_in[4];
    const float* b2 = (const float*)d_in[5];

    int N = in_sizes[0] / DIN;
    int E = in_sizes[1] / 2;
    const int* src = ei;
    const int* dst = ei + E;
    int NB = (N + SCAN_BLK - 1) / SCAN_BLK;

    // workspace layout, 16B-aligned regions
    char* base = (char*)d_ws;
    size_t off = 0;
    int*   deg       = (int*)(base + off);   off = align16(off + (size_t)N * 4);
    int*   partial   = (int*)(base + off);   off = align16(off + (size_t)N * 4);
    int*   rowStart  = (int*)(base + off);   off = align16(off + (size_t)N * 4);
    int*   cursor    = (int*)(base + off);   off = align16(off + (size_t)N * 4);
    int*   blockSums = (int*)(base + off);   off = align16(off + 256 * 4);
    int*   blockOff  = (int*)(base + off);   off = align16(off + 256 * 4);
    float* dinv      = (float*)(base + off); off = align16(off + (size_t)N * 4);
    int*   edgeSrc   = (int*)(base + off);   off = align16(off + (size_t)E * 4);
    float* xg        = (float*)(base + off); off = align16(off + (size_t)N * DIN * 4);
    float* sagg      = (float*)(base + off); off = align16(off + (size_t)N * DIN * 4);
    float* g2        = (float*)(base + off); off = align16(off + (size_t)N * DOUT * 4);

    hipMemsetAsync(deg, 0, (size_t)N * 4, stream);

    {   // int4 count: E/4 lanes
        int EV = (E + 3) / 4;
        k_count_deg<<<(EV + 255) / 256, 256, 0, stream>>>(dst, deg, E);
    }
    k_scan1<<<NB, 256, 0, stream>>>(deg, partial, blockSums, N);
    k_scan2<<<1, 256, 0, stream>>>(blockSums, blockOff, NB);
    k_scan3<<<(N + 255) / 256, 256, 0, stream>>>(partial, blockOff, deg,
                                                 rowStart, cursor, dinv, N);

    // XCD-binned CSR fill: 8 xcd tags x 96 stripes; 2 int4 groups per thread
    k_fill<<<NXCD * 96, 256, 0, stream>>>(src, dst, cursor, edgeSrc, E, N);

    k_xg<<<((size_t)N * 8 + 255) / 256, 256, 0, stream>>>((const float4*)x, dinv,
                                                          (float4*)xg, N);
    k_agg1<<<(N + 3) / 4, 256, 0, stream>>>(rowStart, deg, edgeSrc,
                                            (const float4*)xg, (float4*)sagg, N);
    k_gemm12<<<(N + 255) / 256, 256, 0, stream>>>(sagg, dinv, b1, W1, W2, g2, N);
    k_agg2<<<(N + 3) / 4, 256, 0, stream>>>(rowStart, deg, edgeSrc,
                                            (const float4*)g2, dinv, b2,
                                            (float4*)d_out, N);
}

// Round 12
// 264.323 us; speedup vs baseline: 2.4524x; 1.2220x over previous
//
#include <hip/hip_runtime.h>

#define DIN  32
#define DH   64
#define DOUT 16
#define BKT_SHIFT 10        // 1024 nodes per bucket
#define BKT_NODES 1024
#define MAXBKT 128          // supports N <= 131072
#define PBLK 256            // partition blocks (hist/part must match)

// ---- 1. per-block LDS histogram of dst buckets ------------------------------
__global__ void k_hist(const int* __restrict__ dst, int* __restrict__ hist,
                       int E, int NBKT) {
    __shared__ int h[MAXBKT];
    int tid = threadIdx.x;
    for (int i = tid; i < NBKT; i += blockDim.x) h[i] = 0;
    __syncthreads();
    int nth = gridDim.x * blockDim.x;
    int EV = E >> 2;
    const int4* d4p = (const int4*)dst;
    for (int v = blockIdx.x * blockDim.x + tid; v < EV; v += nth) {
        int4 d = d4p[v];
        atomicAdd(&h[d.x >> BKT_SHIFT], 1);
        atomicAdd(&h[d.y >> BKT_SHIFT], 1);
        atomicAdd(&h[d.z >> BKT_SHIFT], 1);
        atomicAdd(&h[d.w >> BKT_SHIFT], 1);
    }
    if (blockIdx.x == 0 && tid < (E & 3))
        atomicAdd(&h[dst[(E & ~3) + tid] >> BKT_SHIFT], 1);
    __syncthreads();
    for (int i = tid; i < NBKT; i += blockDim.x)
        hist[i * PBLK + blockIdx.x] = h[i];
}

// ---- 2. scan hist (bucket-major) -> per-(block,bucket) offsets + bucketBase -
__global__ void k_scanhist(int* __restrict__ hist, int* __restrict__ bucketBase,
                           int total, int NBKT, int E) {
    __shared__ int s[1024];
    int tid = threadIdx.x;
    int chunk = (total + 1023) >> 10;
    int lo = tid * chunk, hi = min(total, lo + chunk);
    int sum = 0;
    for (int i = lo; i < hi; ++i) sum += hist[i];
    s[tid] = sum;
    __syncthreads();
    for (int off = 1; off < 1024; off <<= 1) {
        int t = (tid >= off) ? s[tid - off] : 0;
        __syncthreads();
        s[tid] += t;
        __syncthreads();
    }
    int run = s[tid] - sum;   // exclusive prefix of this chunk
    for (int i = lo; i < hi; ++i) {
        int v = hist[i];
        if ((i & (PBLK - 1)) == 0) bucketBase[i / PBLK] = run;  // column start
        hist[i] = run;
        run += v;
    }
    if (tid == 0) bucketBase[NBKT] = E;
}

// ---- 3. partition pairs into buckets via block-private LDS cursors ----------
// Each (block,bucket) subrange is private: frontier lines live on ONE CU/XCD
// and fill within the block's pass -> write amplification ~1 by construction.
__global__ void k_part(const int* __restrict__ src, const int* __restrict__ dst,
                       const int* __restrict__ hist, int2* __restrict__ pairs,
                       int E, int NBKT) {
    __shared__ int cur[MAXBKT];
    int tid = threadIdx.x;
    for (int i = tid; i < NBKT; i += blockDim.x)
        cur[i] = hist[i * PBLK + blockIdx.x];
    __syncthreads();
    int nth = gridDim.x * blockDim.x;
    int EV = E >> 2;
    const int4* d4p = (const int4*)dst;
    const int4* s4p = (const int4*)src;
    for (int v = blockIdx.x * blockDim.x + tid; v < EV; v += nth) {
        int4 d = d4p[v];
        int4 s = s4p[v];
        int p;
        p = atomicAdd(&cur[d.x >> BKT_SHIFT], 1); pairs[p] = (int2){s.x, d.x};
        p = atomicAdd(&cur[d.y >> BKT_SHIFT], 1); pairs[p] = (int2){s.y, d.y};
        p = atomicAdd(&cur[d.z >> BKT_SHIFT], 1); pairs[p] = (int2){s.z, d.z};
        p = atomicAdd(&cur[d.w >> BKT_SHIFT], 1); pairs[p] = (int2){s.w, d.w};
    }
    if (blockIdx.x == 0 && tid < (E & 3)) {
        int e = (E & ~3) + tid;
        int d = dst[e];
        int p = atomicAdd(&cur[d >> BKT_SHIFT], 1);
        pairs[p] = (int2){src[e], d};
    }
}

// ---- 4. per-bucket CSR finalize: count+scan+place entirely block-local ------
// Emits rowStart/deg/dinv (replaces count_deg + 3 scan kernels + memset) and
// edgeSrc within a ~65KB block-private window (temporally tight writes).
__global__ void k_build(const int2* __restrict__ pairs, const int* __restrict__ bucketBase,
                        int* __restrict__ rowStart, int* __restrict__ deg,
                        float* __restrict__ dinv, int* __restrict__ edgeSrc,
                        int N, int NBKT) {
    __shared__ int cnt[BKT_NODES];      // 4KB: counts, then reused as cursors
    __shared__ int startloc[BKT_NODES]; // 4KB
    __shared__ int s[512];              // 2KB: block scan
    int b = blockIdx.x;
    int n_lo = b << BKT_SHIFT;
    int nNodes = min(N - n_lo, BKT_NODES);
    int segBase = bucketBase[b];
    int segLen  = bucketBase[b + 1] - segBase;
    int tid = threadIdx.x;   // blockDim = 512

    for (int i = tid; i < nNodes; i += 512) cnt[i] = 0;
    __syncthreads();
    for (int t = tid; t < segLen; t += 512) {
        int2 pr = pairs[segBase + t];
        atomicAdd(&cnt[pr.y - n_lo], 1);
    }
    __syncthreads();
    // exclusive scan of cnt[0..nNodes) : 2 elements per thread
    int i0 = 2 * tid, i1 = 2 * tid + 1;
    int c0 = (i0 < nNodes) ? cnt[i0] : 0;
    int c1 = (i1 < nNodes) ? cnt[i1] : 0;
    s[tid] = c0 + c1;
    __syncthreads();
    for (int off = 1; off < 512; off <<= 1) {
        int t = (tid >= off) ? s[tid - off] : 0;
        __syncthreads();
        s[tid] += t;
        __syncthreads();
    }
    int excl = s[tid] - (c0 + c1);
    if (i0 < nNodes) startloc[i0] = excl;
    if (i1 < nNodes) startloc[i1] = excl + c0;
    __syncthreads();
    // emit rowStart / deg / dinv (coalesced)
    for (int i = tid; i < nNodes; i += 512) {
        int c = cnt[i];
        rowStart[n_lo + i] = segBase + startloc[i];
        deg[n_lo + i]      = c;
        dinv[n_lo + i]     = rsqrtf((float)c + 1.0f);  // +1 self-loop
    }
    __syncthreads();
    for (int i = tid; i < nNodes; i += 512) cnt[i] = startloc[i];  // cursors
    __syncthreads();
    // place edges within the block-private window
    for (int t = tid; t < segLen; t += 512) {
        int2 pr = pairs[segBase + t];
        int p = atomicAdd(&cnt[pr.y - n_lo], 1);
        edgeSrc[segBase + p] = pr.x;
    }
}

// ------------------------------------------ xg = dinv[i] * x[i,:], float4 ---
__global__ void k_xg(const float4* __restrict__ x4, const float* __restrict__ dinv,
                     float4* __restrict__ xg4, int N) {
    int t = blockIdx.x * blockDim.x + threadIdx.x;
    if (t < N * 8) {                       // 8 quads per node
        float d = dinv[t >> 3];
        float4 v = x4[t];
        v.x *= d; v.y *= d; v.z *= d; v.w *= d;
        xg4[t] = v;
    }
}

// ---- layer-1 aggregation: s_i = sum_j xg_j + xg_i ---------------------------
// wave per node. lane = es*8 + fl. Two-stage predicated block (2 latency hops).
__global__ void k_agg1(const int* __restrict__ rowStart, const int* __restrict__ deg,
                       const int* __restrict__ edgeSrc, const float4* __restrict__ xg4,
                       float4* __restrict__ s4, int N) {
    int tid = threadIdx.x;
    int w = tid >> 6, lane = tid & 63;
    int es = lane >> 3, fl = lane & 7;
    int node = blockIdx.x * 4 + w;   // wave-uniform
    if (node >= N) return;

    int s = rowStart[node], c = deg[node];
    float4 a0 = {0,0,0,0}, a1 = {0,0,0,0}, a2 = {0,0,0,0}, a3 = {0,0,0,0};
    int j0 = 0, j1 = 0, j2 = 0, j3 = 0;
    int o0 = es, o1 = 8 + es, o2 = 16 + es, o3 = 24 + es;
    if (o0 < c) j0 = edgeSrc[s + o0];
    if (o1 < c) j1 = edgeSrc[s + o1];
    if (o2 < c) j2 = edgeSrc[s + o2];
    if (o3 < c) j3 = edgeSrc[s + o3];
    if (o0 < c) a0 = xg4[(size_t)j0 * 8 + fl];
    if (o1 < c) a1 = xg4[(size_t)j1 * 8 + fl];
    if (o2 < c) a2 = xg4[(size_t)j2 * 8 + fl];
    if (o3 < c) a3 = xg4[(size_t)j3 * 8 + fl];
    for (int o = 32 + es; o < c; o += 8) {     // rare long tail (deg > 32)
        int j = edgeSrc[s + o];
        float4 v = xg4[(size_t)j * 8 + fl];
        a0.x += v.x; a0.y += v.y; a0.z += v.z; a0.w += v.w;
    }
    float4 A;
    A.x = (a0.x + a1.x) + (a2.x + a3.x);
    A.y = (a0.y + a1.y) + (a2.y + a3.y);
    A.z = (a0.z + a1.z) + (a2.z + a3.z);
    A.w = (a0.w + a1.w) + (a2.w + a3.w);
#pragma unroll
    for (int m = 8; m <= 32; m <<= 1) {
        A.x += __shfl_xor(A.x, m);
        A.y += __shfl_xor(A.y, m);
        A.z += __shfl_xor(A.z, m);
        A.w += __shfl_xor(A.w, m);
    }
    if (es == 0) {
        float4 sl = xg4[(size_t)node * 8 + fl];   // self-loop
        A.x += sl.x; A.y += sl.y; A.z += sl.z; A.w += sl.w;
        s4[(size_t)node * 8 + fl] = A;
    }
}

// ---- dense per-node MLP (one node per lane, zero LDS/shfl) ------------------
__global__ void k_gemm12(const float* __restrict__ sIn, const float* __restrict__ dinv,
                         const float* __restrict__ b1, const float* __restrict__ W1,
                         const float* __restrict__ W2, float* __restrict__ g2, int N) {
    int node = blockIdx.x * blockDim.x + threadIdx.x;
    if (node >= N) return;

    float sv[DIN];
    const float4* s4 = (const float4*)sIn;
#pragma unroll
    for (int q = 0; q < 8; ++q) {
        float4 v = s4[(size_t)node * 8 + q];
        sv[4 * q + 0] = v.x; sv[4 * q + 1] = v.y;
        sv[4 * q + 2] = v.z; sv[4 * q + 3] = v.w;
    }
    float h[DH];
#pragma unroll
    for (int k = 0; k < DH; ++k) h[k] = 0.f;
#pragma unroll
    for (int d = 0; d < DIN; ++d) {
#pragma unroll
        for (int k = 0; k < DH; ++k) h[k] += sv[d] * W1[d * DH + k];
    }
    float di = dinv[node];
#pragma unroll
    for (int k = 0; k < DH; ++k) h[k] = fmaxf(di * h[k] + b1[k], 0.f);
    float g[DOUT];
#pragma unroll
    for (int k = 0; k < DOUT; ++k) g[k] = 0.f;
#pragma unroll
    for (int d = 0; d < DH; ++d) {
#pragma unroll
        for (int k = 0; k < DOUT; ++k) g[k] += h[d] * W2[d * DOUT + k];
    }
    float4* g2_4 = (float4*)g2;
#pragma unroll
    for (int q = 0; q < 4; ++q) {
        float4 r;
        r.x = di * g[4 * q + 0]; r.y = di * g[4 * q + 1];
        r.z = di * g[4 * q + 2]; r.w = di * g[4 * q + 3];
        g2_4[(size_t)node * 4 + q] = r;
    }
}

// ---- layer-2 aggregate + finalize -------------------------------------------
__global__ void k_agg2(const int* __restrict__ rowStart, const int* __restrict__ deg,
                       const int* __restrict__ edgeSrc, const float4* __restrict__ g2_4,
                       const float* __restrict__ dinv, const float* __restrict__ b2,
                       float4* __restrict__ out4, int N) {
    int tid = threadIdx.x;
    int w = tid >> 6, lane = tid & 63;
    int es = lane >> 2, fl = lane & 3;
    int node = blockIdx.x * 4 + w;   // wave-uniform
    if (node >= N) return;

    int s = rowStart[node], c = deg[node];
    float4 a0 = {0,0,0,0}, a1 = {0,0,0,0};
    int j0 = 0, j1 = 0;
    int o0 = es, o1 = 16 + es;
    if (o0 < c) j0 = edgeSrc[s + o0];
    if (o1 < c) j1 = edgeSrc[s + o1];
    if (o0 < c) a0 = g2_4[(size_t)j0 * 4 + fl];
    if (o1 < c) a1 = g2_4[(size_t)j1 * 4 + fl];
    for (int o = 32 + es; o < c; o += 16) {
        int j = edgeSrc[s + o];
        float4 v = g2_4[(size_t)j * 4 + fl];
        a0.x += v.x; a0.y += v.y; a0.z += v.z; a0.w += v.w;
    }
    float4 A;
    A.x = a0.x + a1.x; A.y = a0.y + a1.y; A.z = a0.z + a1.z; A.w = a0.w + a1.w;
#pragma unroll
    for (int m = 4; m <= 32; m <<= 1) {
        A.x += __shfl_xor(A.x, m);
        A.y += __shfl_xor(A.y, m);
        A.z += __shfl_xor(A.z, m);
        A.w += __shfl_xor(A.w, m);
    }
    if (es == 0) {
        float4 sl = g2_4[(size_t)node * 4 + fl];  // self-loop
        A.x += sl.x; A.y += sl.y; A.z += sl.z; A.w += sl.w;
        float d = dinv[node];
        const float4* b2_4 = (const float4*)b2;
        float4 bq = b2_4[fl], r;
        r.x = d * A.x + bq.x; r.y = d * A.y + bq.y;
        r.z = d * A.z + bq.z; r.w = d * A.w + bq.w;
        out4[(size_t)node * 4 + fl] = r;
    }
}

// ----------------------------------------------------------------------------
static inline size_t align16(size_t v) { return (v + 15) & ~(size_t)15; }

extern "C" void kernel_launch(void* const* d_in, const int* in_sizes, int n_in,
                              void* d_out, int out_size, void* d_ws, size_t ws_size,
                              hipStream_t stream) {
    const float* x  = (const float*)d_in[0];
    const int*   ei = (const int*)  d_in[1];
    const float* W1 = (const float*)d_in[2];
    const float* b1 = (const float*)d_in[3];
    const float* W2 = (const float*)d_in[4];
    const float* b2 = (const float*)d_in[5];

    int N = in_sizes[0] / DIN;
    int E = in_sizes[1] / 2;
    const int* src = ei;
    const int* dst = ei + E;
    int NBKT = (N + BKT_NODES - 1) >> BKT_SHIFT;   // 98 for N=100k (<=MAXBKT)

    // workspace layout, 16B-aligned regions
    char* base = (char*)d_ws;
    size_t off = 0;
    int*   hist       = (int*)(base + off);   off = align16(off + (size_t)MAXBKT * PBLK * 4);
    int*   bucketBase = (int*)(base + off);   off = align16(off + (size_t)(MAXBKT + 1) * 4);
    int*   rowStart   = (int*)(base + off);   off = align16(off + (size_t)N * 4);
    int*   deg        = (int*)(base + off);   off = align16(off + (size_t)N * 4);
    float* dinv       = (float*)(base + off); off = align16(off + (size_t)N * 4);
    int*   edgeSrc    = (int*)(base + off);   off = align16(off + (size_t)E * 4);
    float* xg         = (float*)(base + off); off = align16(off + (size_t)N * DIN * 4);
    float* sagg       = (float*)(base + off); off = align16(off + (size_t)N * DIN * 4);
    float* g2         = (float*)(base + off); off = align16(off + (size_t)N * DOUT * 4);
    // pairs (E*8B = 12.8MB) aliases sagg (N*128B = 12.8MB): pairs dead after
    // k_build; sagg first written by k_agg1 (later on same stream)
    int2*  pairs      = (int2*)sagg;

    k_hist    <<<PBLK, 256, 0, stream>>>(dst, hist, E, NBKT);
    k_scanhist<<<1, 1024, 0, stream>>>(hist, bucketBase, NBKT * PBLK, NBKT, E);
    k_part    <<<PBLK, 256, 0, stream>>>(src, dst, hist, pairs, E, NBKT);
    k_build   <<<NBKT, 512, 0, stream>>>(pairs, bucketBase, rowStart, deg, dinv,
                                         edgeSrc, N, NBKT);

    k_xg<<<((size_t)N * 8 + 255) / 256, 256, 0, stream>>>((const float4*)x, dinv,
                                                          (float4*)xg, N);
    k_agg1<<<(N + 3) / 4, 256, 0, stream>>>(rowStart, deg, edgeSrc,
                                            (const float4*)xg, (float4*)sagg, N);
    k_gemm12<<<(N + 255) / 256, 256, 0, stream>>>(sagg, dinv, b1, W1, W2, g2, N);
    k_agg2<<<(N + 3) / 4, 256, 0, stream>>>(rowStart, deg, edgeSrc,
                                            (const float4*)g2, dinv, b2,
                                            (float4*)d_out, N);
}